// Round 1
// baseline (4627.452 us; speedup 1.0000x reference)
//
#include <hip/hip_runtime.h>
#include <hip/hip_bf16.h>

#define V 50257
#define L 4096
#define H1 30
#define H2 50
#define G1N 120   // 4*H1
#define G2N 200   // 4*H2

// ---- workspace layout (float offsets) ----
#define OFF_WIH1 16
#define OFF_WHH1 (OFF_WIH1 + G1N*H1)   // 3616
#define OFF_B1   (OFF_WHH1 + G1N*H1)   // 7216
#define OFF_WC   (OFF_B1 + G1N)        // 7336   Wc = w_ih2 @ w1  [200x30]
#define OFF_BC   (OFF_WC + G2N*H1)     // 13336  bc = w_ih2@bl1 + b_ih2 + b_hh2
#define OFF_WHH2 (OFF_BC + G2N)        // 13536
#define OFF_GX1  (OFF_WHH2 + G2N*H2)   // 23536  [4096 x 120]
#define OFF_H2   (OFF_GX1 + L*G1N)     // 515056 [4096 x 50]
// total ~720k floats = 2.88 MB of d_ws

__device__ __forceinline__ float fast_rcp(float x){
#if __has_builtin(__builtin_amdgcn_rcpf)
  return __builtin_amdgcn_rcpf(x);
#else
  return 1.f/x;
#endif
}
__device__ __forceinline__ float sigf(float x){
  return fast_rcp(1.f + __expf(-x));
}
__device__ __forceinline__ float tanh_f(float x){
  return 2.f*sigf(2.f*x) - 1.f;
}

// LDS-only barrier. __syncthreads() emits s_waitcnt vmcnt(0) lgkmcnt(0)
// before s_barrier; the vmcnt(0) force-drains the per-step h2o global store
// and the gx1 prefetch load inside EVERY recurrence step (~600-1300 cy/step
// exposed L2/HBM latency). All in-loop cross-thread communication is LDS,
// so lgkmcnt(0)+s_barrier suffices; global ops drain only at their uses.
__device__ __forceinline__ void lds_barrier(){
  asm volatile("s_waitcnt lgkmcnt(0)\n\ts_barrier" ::: "memory");
}

template<int BF>
__device__ __forceinline__ float ldN(const void* p, long i){
  if (BF) return __bfloat162float(((const __hip_bfloat16*)p)[i]);
  return ((const float*)p)[i];
}
__device__ __forceinline__ float ldF(const void* p, long i, int bf){
  return bf ? __bfloat162float(((const __hip_bfloat16*)p)[i])
            : ((const float*)p)[i];
}

// ---- kernel 0: on-device dtype detection (fp32 vs bf16) ----
__global__ void k_detect(const unsigned* emb, int* flag){
  __shared__ int cnt;
  if (threadIdx.x == 0) cnt = 0;
  __syncthreads();
  unsigned w = emb[threadIdx.x];
  unsigned e = (w >> 7) & 0xffu;   // bits [14:7] of the low 16-bit half
  int hit = (e >= 90u && e <= 130u) ? 1 : 0;
  atomicAdd(&cnt, hit);
  __syncthreads();
  if (threadIdx.x == 0) *flag = (cnt >= 192) ? 1 : 0;
}

// ---- kernel 1: convert small weights to fp32, fold Linear1 into LSTM2 input ----
__global__ void k_prep(float* ws, const void* w_ih1, const void* w_hh1,
                       const void* b_ih1, const void* b_hh1,
                       const void* w1, const void* bl1,
                       const void* w_ih2, const void* w_hh2,
                       const void* b_ih2, const void* b_hh2){
  int bf = ((const int*)ws)[0];
  int gid = blockIdx.x*blockDim.x + threadIdx.x;
  int gsz = gridDim.x*blockDim.x;
  for (int i=gid; i<G1N*H1; i+=gsz) ws[OFF_WIH1+i] = ldF(w_ih1,i,bf);
  for (int i=gid; i<G1N*H1; i+=gsz) ws[OFF_WHH1+i] = ldF(w_hh1,i,bf);
  for (int i=gid; i<G1N;    i+=gsz) ws[OFF_B1+i]   = ldF(b_ih1,i,bf)+ldF(b_hh1,i,bf);
  for (int i=gid; i<G2N*H2; i+=gsz) ws[OFF_WHH2+i] = ldF(w_hh2,i,bf);
  for (int i=gid; i<G2N; i+=gsz){
    float a = ldF(b_ih2,i,bf) + ldF(b_hh2,i,bf);
    for (int k=0;k<H2;k++) a += ldF(w_ih2,(long)i*H2+k,bf)*ldF(bl1,k,bf);
    ws[OFF_BC+i] = a;
  }
  for (int i=gid; i<G2N*H1; i+=gsz){
    int o = i / H1, j = i % H1;
    float a = 0.f;
    for (int k=0;k<H2;k++) a += ldF(w_ih2,(long)o*H2+k,bf)*ldF(w1,(long)k*H1+j,bf);
    ws[OFF_WC+i] = a;
  }
}

// ---- kernel 2: embedding gather + gx1 = emb[x] @ w_ih1^T + (b_ih1+b_hh1) ----
__global__ void k_embed(const int* __restrict__ x, const void* __restrict__ emb,
                        float* __restrict__ ws){
  int bf = ((const int*)ws)[0];
  __shared__ float er[2][H1];
  int half = threadIdx.x >> 7;       // 2 timesteps per block
  int lane = threadIdx.x & 127;
  int t = blockIdx.x*2 + half;
  int idx = x[t];
  if (lane < H1) er[half][lane] = ldF(emb,(long)idx*H1+lane,bf);
  __syncthreads();
  if (lane < G1N){
    const float* wi = ws + OFF_WIH1 + lane*H1;
    float a = ws[OFF_B1 + lane];
    #pragma unroll
    for (int k=0;k<H1;k++) a += er[half][k]*wi[k];
    ws[OFF_GX1 + (long)t*G1N + lane] = a;
  }
}

// ---- kernel 3: fused serial recurrence, lag-1 pipeline of LSTM1 & LSTM2 ----
// tid 0..119   : LSTM1 gates (step t),   weights w[0..29]
// tid 128..327 : LSTM2 gates (step t-1), w[0..29]=Wc row, w[32..81]=w_hh2 row
// tid 0..29    : c1/h1 update            tid 64..113 : c2/h2 update
__global__ __launch_bounds__(384) void k_recur(float* __restrict__ ws){
  const float* whh1 = ws + OFF_WHH1;
  const float* wcm  = ws + OFF_WC;
  const float* bcm  = ws + OFF_BC;
  const float* whh2 = ws + OFF_WHH2;
  const float* gx1  = ws + OFF_GX1;
  float* h2o = ws + OFF_H2;

  __shared__ __align__(16) float h1s[32];   // 30 + zero pad
  __shared__ __align__(16) float h2s[52];   // 50 + zero pad
  __shared__ float g1s[G1N];
  __shared__ float g2s[G2N];

  int tid = threadIdx.x;
  bool g1l = (tid < G1N);
  bool g2l = (tid >= 128) && (tid < 128 + G2N);
  int o2 = tid - 128;

  float w[84];
  #pragma unroll
  for (int k=0;k<84;k++) w[k] = 0.f;   // pads must be 0 (multiply vs. padded h)
  float bcv = 0.f;
  if (g1l){
    #pragma unroll
    for (int k=0;k<H1;k++) w[k] = whh1[tid*H1+k];
  } else if (g2l){
    #pragma unroll
    for (int k=0;k<H1;k++) w[k] = wcm[o2*H1+k];
    #pragma unroll
    for (int k=0;k<H2;k++) w[32+k] = whh2[o2*H2+k];
    bcv = bcm[o2];
  }
  bool u1l = (tid < H1);
  bool u2l = (tid >= 64) && (tid < 64 + H2);
  int j2 = tid - 64;
  float c1 = 0.f, c2 = 0.f;
  if (tid < 32) h1s[tid] = 0.f;
  if (tid < 52) h2s[tid] = 0.f;
  __syncthreads();

  float gv = g1l ? gx1[tid] : 0.f;   // prefetched gx1 row for step t
  for (int t=0; t<=L; ++t){
    // prefetch next gx1 row; latency hidden by a full iteration
    float gvn = (g1l && (t+1 < L)) ? gx1[(long)(t+1)*G1N + tid] : 0.f;

    if (g1l && t < L){
      float a0=gv, a1=0.f, a2=0.f, a3=0.f;
      const float4* hp = (const float4*)h1s;
      #pragma unroll
      for (int i=0;i<8;i++){
        float4 h4 = hp[i];
        a0 += w[4*i+0]*h4.x; a1 += w[4*i+1]*h4.y;
        a2 += w[4*i+2]*h4.z; a3 += w[4*i+3]*h4.w;
      }
      g1s[tid] = (a0+a1)+(a2+a3);
    }
    if (g2l && t >= 1){
      float a0=bcv, a1=0.f, a2=0.f, a3=0.f;
      const float4* hp = (const float4*)h1s;
      #pragma unroll
      for (int i=0;i<8;i++){
        float4 h4 = hp[i];
        a0 += w[4*i+0]*h4.x; a1 += w[4*i+1]*h4.y;
        a2 += w[4*i+2]*h4.z; a3 += w[4*i+3]*h4.w;
      }
      const float4* hq = (const float4*)h2s;
      #pragma unroll
      for (int i=0;i<13;i++){
        float4 h4 = hq[i];
        a0 += w[32+4*i+0]*h4.x; a1 += w[32+4*i+1]*h4.y;
        a2 += w[32+4*i+2]*h4.z; a3 += w[32+4*i+3]*h4.w;
      }
      g2s[o2] = (a0+a1)+(a2+a3);
    }
    lds_barrier();

    if (u1l && t < L){
      float gi=g1s[tid], gf=g1s[H1+tid], gg=g1s[2*H1+tid], go=g1s[3*H1+tid];
      c1 = sigf(gf)*c1 + sigf(gi)*tanh_f(gg);
      h1s[tid] = sigf(go)*tanh_f(c1);
    }
    if (u2l && t >= 1){
      float gi=g2s[j2], gf=g2s[H2+j2], gg=g2s[2*H2+j2], go=g2s[3*H2+j2];
      c2 = sigf(gf)*c2 + sigf(gi)*tanh_f(gg);
      float h = sigf(go)*tanh_f(c2);
      h2s[j2] = h;
      h2o[(long)(t-1)*H2 + j2] = h;   // fire-and-forget
    }
    lds_barrier();
    gv = gvn;
  }
}

// ---- kernel 4: out[r][c] = h2[r] . w2[c] + bl2[c]  (2 cols/thread) ----
template<int BF>
__device__ void gemm_body(const float* __restrict__ ws, const void* __restrict__ w2,
                          const void* __restrict__ bl2, void* __restrict__ outv){
  const float* __restrict__ h2 = ws + OFF_H2;
  int c  = blockIdx.x*512 + threadIdx.x*2;
  int r0 = blockIdx.y*128;
  long ca = (c   < V) ? c   : (V-1);
  long cb = (c+1 < V) ? c+1 : (V-1);
  float wa[H2], wb[H2];
  #pragma unroll
  for (int k=0;k<H2;k++){ wa[k]=ldN<BF>(w2, ca*H2+k); wb[k]=ldN<BF>(w2, cb*H2+k); }
  float bav = ldN<BF>(bl2, ca), bbv = ldN<BF>(bl2, cb);
  bool va = (c < V), vb = (c+1 < V);
  for (int r=r0; r<r0+128; ++r){
    const float* __restrict__ h = h2 + (long)r*H2;   // wave-uniform -> s_load
    float a0=bav, a1=0.f, b0=bbv, b1=0.f;
    #pragma unroll
    for (int k=0;k<H2;k+=2){
      float h0=h[k], h1v=h[k+1];
      a0 += h0*wa[k];   a1 += h1v*wa[k+1];
      b0 += h0*wb[k];   b1 += h1v*wb[k+1];
    }
    float ra = a0+a1, rb = b0+b1;
    long base = (long)r*V;
    if (BF){
      __hip_bfloat16* o = (__hip_bfloat16*)outv;
      if (va) o[base+c]   = __float2bfloat16(ra);
      if (vb) o[base+c+1] = __float2bfloat16(rb);
    } else {
      float* o = (float*)outv;
      if (va) o[base+c]   = ra;
      if (vb) o[base+c+1] = rb;
    }
  }
}

__global__ __launch_bounds__(256) void k_gemm(const float* __restrict__ ws,
                                              const void* __restrict__ w2,
                                              const void* __restrict__ bl2,
                                              void* __restrict__ outv){
  if (((const int*)ws)[0]) gemm_body<1>(ws, w2, bl2, outv);
  else                     gemm_body<0>(ws, w2, bl2, outv);
}

extern "C" void kernel_launch(void* const* d_in, const int* in_sizes, int n_in,
                              void* d_out, int out_size, void* d_ws, size_t ws_size,
                              hipStream_t stream){
  const int* x = (const int*)d_in[0];
  const void* emb = d_in[1];
  float* ws = (float*)d_ws;

  k_detect<<<1, 256, 0, stream>>>((const unsigned*)emb, (int*)d_ws);
  k_prep<<<64, 256, 0, stream>>>(ws, d_in[2], d_in[3], d_in[4], d_in[5],
                                 d_in[6], d_in[7], d_in[8], d_in[9],
                                 d_in[10], d_in[11]);
  k_embed<<<L/2, 256, 0, stream>>>(x, emb, ws);
  k_recur<<<1, 384, 0, stream>>>(ws);
  dim3 g((V + 511)/512, L/128);
  k_gemm<<<g, 256, 0, stream>>>(ws, d_in[12], d_in[13], d_out);
}

// Round 4
// 4453.535 us; speedup vs baseline: 1.0391x; 1.0391x over previous
//
#include <hip/hip_runtime.h>
#include <hip/hip_bf16.h>

#define V 50257
#define L 4096
#define H1 30
#define H2 50
#define G1N 120   // 4*H1
#define G2N 200   // 4*H2

// ---- workspace layout (float offsets) ----
#define OFF_WIH1 16
#define OFF_WHH1 (OFF_WIH1 + G1N*H1)   // 3616
#define OFF_B1   (OFF_WHH1 + G1N*H1)   // 7216
#define OFF_WC   (OFF_B1 + G1N)        // 7336   Wc = w_ih2 @ w1  [200x30]
#define OFF_BC   (OFF_WC + G2N*H1)     // 13336  bc = w_ih2@bl1 + b_ih2 + b_hh2
#define OFF_WHH2 (OFF_BC + G2N)        // 13536
#define OFF_GX1  (OFF_WHH2 + G2N*H2)   // 23536  [4096 x 120] (PERMUTED rows)
#define OFF_H2   (OFF_GX1 + L*G1N)     // 515056 [4096 x 50]

__device__ __forceinline__ float fast_rcp(float x){
#if __has_builtin(__builtin_amdgcn_rcpf)
  return __builtin_amdgcn_rcpf(x);
#else
  return 1.f/x;
#endif
}
__device__ __forceinline__ float sigf(float x){
  return fast_rcp(1.f + __expf(-x));
}
__device__ __forceinline__ float tanh_f(float x){
  return 2.f*sigf(2.f*x) - 1.f;
}

__device__ __forceinline__ float dot4(float4 a, float4 b){
  return a.x*b.x + a.y*b.y + a.z*b.z + a.w*b.w;
}
__device__ __forceinline__ float4 ld4(const float* r){
  return float4{r[0], r[1], r[2], r[3]};
}
__device__ __forceinline__ float4 ld2z(const float* r){
  return float4{r[0], r[1], 0.f, 0.f};
}

// All-gather the 4 gate values within a 4-lane group (lane = 4*out + q).
// 3 shuffles + cndmask remap -> every lane gets (gi,gf,gg,go).
__device__ __forceinline__ void gather4(float a, int q,
                                        float& gi, float& gf, float& gg, float& go){
  float t1 = __shfl_xor(a, 1);   // gate q^1
  float u1 = __shfl_xor(a, 2);   // gate q^2
  float v1 = __shfl_xor(t1, 2);  // gate q^3
  float e0 = (q&1) ? t1 : a;     // gate (q&2)
  float e1 = (q&1) ? a  : t1;    // gate (q&2)+1
  float f0 = (q&1) ? v1 : u1;    // gate (q&2)^2
  float f1 = (q&1) ? u1 : v1;    // gate ((q&2)^2)+1
  gi = (q&2) ? f0 : e0;
  gf = (q&2) ? f1 : e1;
  gg = (q&2) ? e0 : f0;
  go = (q&2) ? e1 : f1;
}

template<int BF>
__device__ __forceinline__ float ldN(const void* p, long i){
  if (BF) return __bfloat162float(((const __hip_bfloat16*)p)[i]);
  return ((const float*)p)[i];
}
__device__ __forceinline__ float ldF(const void* p, long i, int bf){
  return bf ? __bfloat162float(((const __hip_bfloat16*)p)[i])
            : ((const float*)p)[i];
}

// ---- kernel 0: on-device dtype detection (fp32 vs bf16) ----
__global__ void k_detect(const unsigned* emb, int* flag){
  __shared__ int cnt;
  if (threadIdx.x == 0) cnt = 0;
  __syncthreads();
  unsigned w = emb[threadIdx.x];
  unsigned e = (w >> 7) & 0xffu;
  int hit = (e >= 90u && e <= 130u) ? 1 : 0;
  atomicAdd(&cnt, hit);
  __syncthreads();
  if (threadIdx.x == 0) *flag = (cnt >= 192) ? 1 : 0;
}

// ---- kernel 1: convert small weights to fp32, fold Linear1 into LSTM2 input ----
__global__ void k_prep(float* ws, const void* w_ih1, const void* w_hh1,
                       const void* b_ih1, const void* b_hh1,
                       const void* w1, const void* bl1,
                       const void* w_ih2, const void* w_hh2,
                       const void* b_ih2, const void* b_hh2){
  int bf = ((const int*)ws)[0];
  int gid = blockIdx.x*blockDim.x + threadIdx.x;
  int gsz = gridDim.x*blockDim.x;
  for (int i=gid; i<G1N*H1; i+=gsz) ws[OFF_WIH1+i] = ldF(w_ih1,i,bf);
  for (int i=gid; i<G1N*H1; i+=gsz) ws[OFF_WHH1+i] = ldF(w_hh1,i,bf);
  for (int i=gid; i<G1N;    i+=gsz) ws[OFF_B1+i]   = ldF(b_ih1,i,bf)+ldF(b_hh1,i,bf);
  for (int i=gid; i<G2N*H2; i+=gsz) ws[OFF_WHH2+i] = ldF(w_hh2,i,bf);
  for (int i=gid; i<G2N; i+=gsz){
    float a = ldF(b_ih2,i,bf) + ldF(b_hh2,i,bf);
    for (int k=0;k<H2;k++) a += ldF(w_ih2,(long)i*H2+k,bf)*ldF(bl1,k,bf);
    ws[OFF_BC+i] = a;
  }
  for (int i=gid; i<G2N*H1; i+=gsz){
    int o = i / H1, j = i % H1;
    float a = 0.f;
    for (int k=0;k<H2;k++) a += ldF(w_ih2,(long)o*H2+k,bf)*ldF(w1,(long)k*H1+j,bf);
    ws[OFF_WC+i] = a;
  }
}

// ---- kernel 2: embedding gather + gx1 = emb[x] @ w_ih1^T + (b_ih1+b_hh1) ----
// Writes gx1 rows PERMUTED: value for (gate q, out j) lands at column 4*j+q,
// so k_recur lane tid reads its own gate input at gx1[t*120 + tid] (coalesced).
__global__ void k_embed(const int* __restrict__ x, const void* __restrict__ emb,
                        float* __restrict__ ws){
  int bf = ((const int*)ws)[0];
  __shared__ float er[2][H1];
  int half = threadIdx.x >> 7;       // 2 timesteps per block
  int lane = threadIdx.x & 127;
  int t = blockIdx.x*2 + half;
  int idx = x[t];
  if (lane < H1) er[half][lane] = ldF(emb,(long)idx*H1+lane,bf);
  __syncthreads();
  if (lane < G1N){
    const float* wi = ws + OFF_WIH1 + lane*H1;
    float a = ws[OFF_B1 + lane];
    #pragma unroll
    for (int k=0;k<H1;k++) a += er[half][k]*wi[k];
    int pi = 4*(lane % 30) + lane / 30;      // permuted column
    ws[OFF_GX1 + (long)t*G1N + pi] = a;
  }
}

// ---- kernel 3: fused serial recurrence, lag-1 pipeline, single barrier/step ----
// tid 0..119  : LSTM1, lane = 4*j+q computes gate q of output j (step t)
// tid 128..327: LSTM2, lane = 128+4*k+q computes gate q of output k (step t-1)
// Gates gathered within the 4-lane group via shuffles; update computed
// redundantly in all 4 lanes; q==0 leader publishes h to double-buffered LDS.
// Weights live in 21 NAMED float4 registers (the old float w[84] array was
// allocated to scratch -> VGPR_Count 68 -> per-step L2 reloads dominated).
__global__ __launch_bounds__(384) void k_recur(float* __restrict__ ws){
  const float* whh1 = ws + OFF_WHH1;
  const float* wcm  = ws + OFF_WC;
  const float* bcm  = ws + OFF_BC;
  const float* whh2 = ws + OFF_WHH2;
  const float* gx1  = ws + OFF_GX1;
  float* h2o = ws + OFF_H2;

  __shared__ __align__(16) float hb1[2][32];   // h1 double buffer (30 + pad)
  __shared__ __align__(16) float hb2[2][52];   // h2 double buffer (50 + pad)

  int tid = threadIdx.x;
  bool g1l = (tid < G1N);
  bool g2l = (tid >= 128) && (tid < 128 + G2N);
  int rel = tid - 128;
  int q1 = tid & 3,  j1 = tid >> 2;        // LSTM1: gate q1, output j1
  int q2 = rel & 3,  k2 = rel >> 2;        // LSTM2: gate q2, output k2

  // 21 named float4 weight registers (zero pads => safe vs padded h entries)
  float4 w0{0,0,0,0}, w1{0,0,0,0}, w2{0,0,0,0}, w3{0,0,0,0};
  float4 w4{0,0,0,0}, w5{0,0,0,0}, w6{0,0,0,0}, w7{0,0,0,0};
  float4 v0{0,0,0,0}, v1{0,0,0,0}, v2{0,0,0,0}, v3{0,0,0,0};
  float4 v4{0,0,0,0}, v5{0,0,0,0}, v6{0,0,0,0}, v7{0,0,0,0};
  float4 v8{0,0,0,0}, v9{0,0,0,0}, v10{0,0,0,0}, v11{0,0,0,0}, v12{0,0,0,0};
  float bcv = 0.f;

  if (g1l){
    const float* r = whh1 + (30*q1 + j1)*H1;   // row 30*q1+j1 of w_hh1
    w0=ld4(r); w1=ld4(r+4); w2=ld4(r+8); w3=ld4(r+12);
    w4=ld4(r+16); w5=ld4(r+20); w6=ld4(r+24); w7=ld2z(r+28);
  } else if (g2l){
    int row = 50*q2 + k2;
    const float* r  = wcm  + row*H1;           // Wc row (vs h1, 30)
    const float* r2 = whh2 + row*H2;           // w_hh2 row (vs h2, 50)
    w0=ld4(r); w1=ld4(r+4); w2=ld4(r+8); w3=ld4(r+12);
    w4=ld4(r+16); w5=ld4(r+20); w6=ld4(r+24); w7=ld2z(r+28);
    v0=ld4(r2); v1=ld4(r2+4); v2=ld4(r2+8); v3=ld4(r2+12);
    v4=ld4(r2+16); v5=ld4(r2+20); v6=ld4(r2+24); v7=ld4(r2+28);
    v8=ld4(r2+32); v9=ld4(r2+36); v10=ld4(r2+40); v11=ld4(r2+44);
    v12=ld2z(r2+48);
    bcv = bcm[row];
  }

  float c1 = 0.f, c2 = 0.f;
  { // zero both double buffers (incl. pads)
    float* f1 = (float*)hb1;
    float* f2 = (float*)hb2;
    if (tid < 64)  f1[tid] = 0.f;
    if (tid < 104) f2[tid] = 0.f;
  }
  __syncthreads();

  float gv = g1l ? gx1[tid] : 0.f;   // prefetched (permuted) gx1 row, step 0
  int p = 0;
  for (int t=0; t<=L; ++t){
    float gvn = (g1l && (t+1 < L)) ? gx1[(long)(t+1)*G1N + tid] : 0.f;
    const float* h1r = hb1[p];
    const float* h2r = hb2[p];
    float* h1w = hb1[p^1];
    float* h2w = hb2[p^1];

    if (g1l && t < L){
      const float4* hp = (const float4*)h1r;
      float4 x0=hp[0], x1=hp[1], x2=hp[2], x3=hp[3];
      float4 x4=hp[4], x5=hp[5], x6=hp[6], x7=hp[7];
      float a0 = gv + dot4(w0,x0) + dot4(w4,x4);
      float a1 =      dot4(w1,x1) + dot4(w5,x5);
      float a2 =      dot4(w2,x2) + dot4(w6,x6);
      float a3 =      dot4(w3,x3) + dot4(w7,x7);
      float gval = (a0+a1)+(a2+a3);
      float gi,gf,gg,go;
      gather4(gval, q1, gi, gf, gg, go);
      c1 = sigf(gf)*c1 + sigf(gi)*tanh_f(gg);
      float h = sigf(go)*tanh_f(c1);
      if (q1 == 0) h1w[j1] = h;
    }
    if (g2l && t >= 1){
      const float4* hp = (const float4*)h1r;
      const float4* hq = (const float4*)h2r;
      float4 x0=hp[0], x1=hp[1], x2=hp[2], x3=hp[3];
      float4 x4=hp[4], x5=hp[5], x6=hp[6], x7=hp[7];
      float4 y0=hq[0], y1=hq[1], y2=hq[2], y3=hq[3];
      float4 y4=hq[4], y5=hq[5], y6=hq[6], y7=hq[7];
      float4 y8=hq[8], y9=hq[9], y10=hq[10], y11=hq[11], y12=hq[12];
      float a0 = bcv + dot4(w0,x0) + dot4(w4,x4)
                     + dot4(v0,y0) + dot4(v4,y4) + dot4(v8,y8) + dot4(v12,y12);
      float a1 =       dot4(w1,x1) + dot4(w5,x5)
                     + dot4(v1,y1) + dot4(v5,y5) + dot4(v9,y9);
      float a2 =       dot4(w2,x2) + dot4(w6,x6)
                     + dot4(v2,y2) + dot4(v6,y6) + dot4(v10,y10);
      float a3 =       dot4(w3,x3) + dot4(w7,x7)
                     + dot4(v3,y3) + dot4(v7,y7) + dot4(v11,y11);
      float gval = (a0+a1)+(a2+a3);
      float gi,gf,gg,go;
      gather4(gval, q2, gi, gf, gg, go);
      c2 = sigf(gf)*c2 + sigf(gi)*tanh_f(gg);
      float h = sigf(go)*tanh_f(c2);
      if (q2 == 0){
        h2w[k2] = h;
        h2o[(long)(t-1)*H2 + k2] = h;   // fire-and-forget
      }
    }
    __syncthreads();
    gv = gvn;
    p ^= 1;
  }
}

// ---- kernel 4: out[r][c] = h2[r] . w2[c] + bl2[c]  (2 cols/thread) ----
template<int BF>
__device__ void gemm_body(const float* __restrict__ ws, const void* __restrict__ w2,
                          const void* __restrict__ bl2, void* __restrict__ outv){
  const float* __restrict__ h2 = ws + OFF_H2;
  int c  = blockIdx.x*512 + threadIdx.x*2;
  int r0 = blockIdx.y*128;
  long ca = (c   < V) ? c   : (V-1);
  long cb = (c+1 < V) ? c+1 : (V-1);
  float wa[H2], wb[H2];
  #pragma unroll
  for (int k=0;k<H2;k++){ wa[k]=ldN<BF>(w2, ca*H2+k); wb[k]=ldN<BF>(w2, cb*H2+k); }
  float bav = ldN<BF>(bl2, ca), bbv = ldN<BF>(bl2, cb);
  bool va = (c < V), vb = (c+1 < V);
  for (int r=r0; r<r0+128; ++r){
    const float* __restrict__ h = h2 + (long)r*H2;
    float a0=bav, a1=0.f, b0=bbv, b1=0.f;
    #pragma unroll
    for (int k=0;k<H2;k+=2){
      float h0=h[k], h1v=h[k+1];
      a0 += h0*wa[k];   a1 += h1v*wa[k+1];
      b0 += h0*wb[k];   b1 += h1v*wb[k+1];
    }
    float ra = a0+a1, rb = b0+b1;
    long base = (long)r*V;
    if (BF){
      __hip_bfloat16* o = (__hip_bfloat16*)outv;
      if (va) o[base+c]   = __float2bfloat16(ra);
      if (vb) o[base+c+1] = __float2bfloat16(rb);
    } else {
      float* o = (float*)outv;
      if (va) o[base+c]   = ra;
      if (vb) o[base+c+1] = rb;
    }
  }
}

__global__ __launch_bounds__(256) void k_gemm(const float* __restrict__ ws,
                                              const void* __restrict__ w2,
                                              const void* __restrict__ bl2,
                                              void* __restrict__ outv){
  if (((const int*)ws)[0]) gemm_body<1>(ws, w2, bl2, outv);
  else                     gemm_body<0>(ws, w2, bl2, outv);
}

extern "C" void kernel_launch(void* const* d_in, const int* in_sizes, int n_in,
                              void* d_out, int out_size, void* d_ws, size_t ws_size,
                              hipStream_t stream){
  const int* x = (const int*)d_in[0];
  const void* emb = d_in[1];
  float* ws = (float*)d_ws;

  k_detect<<<1, 256, 0, stream>>>((const unsigned*)emb, (int*)d_ws);
  k_prep<<<64, 256, 0, stream>>>(ws, d_in[2], d_in[3], d_in[4], d_in[5],
                                 d_in[6], d_in[7], d_in[8], d_in[9],
                                 d_in[10], d_in[11]);
  k_embed<<<L/2, 256, 0, stream>>>(x, emb, ws);
  k_recur<<<1, 384, 0, stream>>>(ws);
  dim3 g((V + 511)/512, L/128);
  k_gemm<<<g, 256, 0, stream>>>(ws, d_in[12], d_in[13], d_out);
}